// Round 3
// baseline (2824.674 us; speedup 1.0000x reference)
//
#include <hip/hip_runtime.h>
#include <math.h>

#define BB 4
#define NP 8192
#define CF 64
#define MQ 2048
#define KS 32

// ---- workspace layout (float indices) ----
#define WS_FT     0u         // ft: [B][N][64] transposed features (2097152 floats)
#define WS_NIDX   2097152u   // nidx: [B][M][K] int (262144)
#define WS_IDXI   2359296u   // idx int copy: [B][M] (8192)
#define WS_ST1    2367488u   // stats1 slices: [64][2][64] (8192)
#define WS_ST2    2375680u   // stats2 slices: [64][2][128] (16384)
#define WS_SC1    2392064u   // scale/shift bn1: [2][64] (128)
#define WS_SC2    2392192u   // scale/shift bn2: [2][128] (256)
#define WS_MAXY2  2392448u   // maxy2: [B*M][128] (1048576)
#define WS_W1P    3441024u   // padded w1: [64][68] (4352)

// ------------------------------------------------------------------
// transpose f [B][64][N] -> ft [B][N][64]
// ------------------------------------------------------------------
__global__ __launch_bounds__(256) void transpose_f_kernel(
    const float* __restrict__ f, float* __restrict__ ft) {
  __shared__ float tile[64][65];
  int b = blockIdx.y;
  int n0 = blockIdx.x * 64;
  int cc = threadIdx.x >> 6;   // 0..3
  int nn = threadIdx.x & 63;
  #pragma unroll
  for (int r = 0; r < 16; ++r) {
    int c = cc * 16 + r;
    tile[c][nn] = f[((size_t)b * 64 + c) * NP + n0 + nn];
  }
  __syncthreads();
  #pragma unroll
  for (int r = 0; r < 16; ++r) {
    int nl = cc * 16 + r;
    ft[((size_t)b * NP + n0 + nl) * 64 + nn] = tile[nn][nl];
  }
}

// ------------------------------------------------------------------
// pad w1 [64][67] -> w1p [64][68] (last col 0), 16B-aligned rows
// ------------------------------------------------------------------
__global__ void prep_w1_kernel(const float* __restrict__ w1, float* __restrict__ w1p) {
  int i = blockIdx.x * 256 + threadIdx.x;
  if (i < 64 * 68) {
    int o = i / 68, c = i % 68;
    w1p[i] = (c < 67) ? w1[o * 67 + c] : 0.0f;
  }
}

// ------------------------------------------------------------------
// FPS v3: one 1024-thread WG per batch, 8 points/thread in registers.
// 4 waves/SIMD for latency hiding (r2 ran 1 wave/SIMD: ~1700cy/iter of
// exposed dependency/LDS latency).
// Exact-match math (rn sub/mul/add + fminf, no FMA) -> bit-identical
// dmin vs numpy; first-occurrence argmax via packed u64 key
// (f32bits(dmin)<<32 | ~idx): dmin >= 0 so bits are order-preserving,
// max picks largest dmin, ties -> largest ~idx = smallest idx.
// Tail: 6-level u64 shuffle tree per wave, then ONE ds atomicMax per
// wave into a triple-buffered LDS slot; single barrier per iteration.
// Triple-buffer protocol: iter j atomic-maxes cnd[j%3]; post-barrier
// all read cnd[j%3]; thread0 resets cnd[(j+2)%3] (last read at iter
// j-3, next atomics at iter j+2 after barrier(j+1) -> race-free).
// ------------------------------------------------------------------
#define FPS_T 1024
#define PPT 8
__global__ __launch_bounds__(1024, 1) void fps_kernel(
    const float* __restrict__ p, float* __restrict__ out, int* __restrict__ idx_i) {
  __shared__ float spx[NP], spy[NP], spz[NP];               // 96 KB
  __shared__ unsigned long long cnd[3];
  int b = blockIdx.x;
  const float* pb = p + (size_t)b * NP * 3;
  float* out_newp = out;                               // [B][M][3]
  float* out_idxf = out + BB*MQ*3 + (size_t)BB*128*MQ; // [B][M] as float
  int t = threadIdx.x;

  float px[PPT], py[PPT], pz[PPT], dmin[PPT];
  unsigned notI[PPT];
  #pragma unroll
  for (int s = 0; s < PPT; ++s) {
    int i = s * FPS_T + t;
    float x = pb[i*3+0], y = pb[i*3+1], z = pb[i*3+2];
    px[s] = x; py[s] = y; pz[s] = z;
    spx[i] = x; spy[i] = y; spz[i] = z;
    dmin[s] = INFINITY;
    notI[s] = ~(unsigned)i;
  }
  if (t < 3) cnd[t] = 0ull;
  __syncthreads();
  float lx = spx[0], ly = spy[0], lz = spz[0];
  if (t == 0) {
    out_idxf[b*MQ] = 0.0f;
    idx_i[b*MQ] = 0;
    out_newp[(size_t)(b*MQ)*3 + 0] = lx;
    out_newp[(size_t)(b*MQ)*3 + 1] = ly;
    out_newp[(size_t)(b*MQ)*3 + 2] = lz;
  }

  for (int j = 1; j < MQ; ++j) {
    unsigned long long key = 0ull;
    #pragma unroll
    for (int s = 0; s < PPT; ++s) {
      float dx = __fsub_rn(px[s], lx);
      float dy = __fsub_rn(py[s], ly);
      float dz = __fsub_rn(pz[s], lz);
      float d = __fadd_rn(__fadd_rn(__fmul_rn(dx,dx), __fmul_rn(dy,dy)), __fmul_rn(dz,dz));
      float dm = fminf(dmin[s], d);
      dmin[s] = dm;
      unsigned long long k =
          ((unsigned long long)__float_as_uint(dm) << 32) | (unsigned long long)notI[s];
      key = k > key ? k : key;
    }
    #pragma unroll
    for (int off = 32; off >= 1; off >>= 1) {
      unsigned long long ok = __shfl_xor(key, off);
      if (ok > key) key = ok;
    }
    int slot = j % 3;
    if ((t & 63) == 0) atomicMax(&cnd[slot], key);
    __syncthreads();
    unsigned long long kw = cnd[slot];
    if (t == 0) cnd[(j + 2) % 3] = 0ull;
    int wi = (int)(~(unsigned)kw);
    lx = spx[wi]; ly = spy[wi]; lz = spz[wi];   // LDS broadcast (same addr)
    if (t == 0) {
      out_idxf[b*MQ + j] = (float)wi;
      idx_i[b*MQ + j] = wi;
      float* np_ = &out_newp[(size_t)(b*MQ + j) * 3];
      np_[0] = lx; np_[1] = ly; np_[2] = lz;
    }
  }
}

// ------------------------------------------------------------------
// ball query: one wave per query. Mirrors |q|^2+|p|^2-2*dot with rn
// ops; threshold is float( double(0.1)*double(0.1) ).
// ------------------------------------------------------------------
__global__ __launch_bounds__(256) void ballq_kernel(
    const float* __restrict__ p, const float* __restrict__ newp,
    int* __restrict__ nidx) {
  int qid = blockIdx.x * 4 + (threadIdx.x >> 6);   // b*M+m
  int lane = threadIdx.x & 63;
  int b = qid >> 11;
  const float* pb = p + (size_t)b * NP * 3;
  float qx = newp[qid*3], qy = newp[qid*3+1], qz = newp[qid*3+2];
  float sq_q = __fadd_rn(__fadd_rn(__fmul_rn(qx,qx), __fmul_rn(qy,qy)), __fmul_rn(qz,qz));
  const float R2 = (float)(0.1 * 0.1);   // 0.009999999776482582f
  int found = 0, first = -1;
  int* outp = nidx + (size_t)qid * KS;
  for (int base = 0; base < NP; base += 64) {
    int n = base + lane;
    float x = pb[n*3], y = pb[n*3+1], z = pb[n*3+2];
    float sq_p = __fadd_rn(__fadd_rn(__fmul_rn(x,x), __fmul_rn(y,y)), __fmul_rn(z,z));
    float dot  = __fadd_rn(__fadd_rn(__fmul_rn(qx,x), __fmul_rn(qy,y)), __fmul_rn(qz,z));
    float d2   = __fadd_rn(__fadd_rn(sq_q, sq_p), __fmul_rn(-2.0f, dot));
    bool hit = d2 < R2;
    unsigned long long mask = __ballot(hit);
    if (mask) {
      if (first < 0) first = base + __builtin_ctzll(mask);
      int cnt = __popcll(mask);
      if (found < KS) {
        int rank = __popcll(mask & ((1ull << lane) - 1ull));
        if (hit && found + rank < KS) outp[found + rank] = n;
      }
      found += cnt;
      if (found >= KS) break;
    }
  }
  int fcl = found < KS ? found : KS;
  int padv = first < 0 ? 0 : first;
  if (lane >= fcl && lane < KS) outp[lane] = padv;
}

// ------------------------------------------------------------------
// P1: conv1 over gathered x, accumulate per-channel sum/sumsq.
// One wave per query, lane = output channel.
// ------------------------------------------------------------------
__global__ __launch_bounds__(256) void p1_kernel(
    const float* __restrict__ p, const float* __restrict__ newp,
    const float* __restrict__ ft, const int* __restrict__ nidx,
    const float* __restrict__ w1p, float* __restrict__ stats1) {
  __shared__ __align__(16) float xbuf[4][KS][68];
  __shared__ float wbs[4][64], wbq[4][64];
  int wv = threadIdx.x >> 6, lane = threadIdx.x & 63;
  int qid = blockIdx.x * 4 + wv;
  int b = qid >> 11;
  // gather x = [dp(3) | fj(64) | 0]
  int nv = (lane < KS) ? nidx[(size_t)qid * KS + lane] : 0;
  float qx = newp[qid*3], qy = newp[qid*3+1], qz = newp[qid*3+2];
  for (int kk = 0; kk < KS; ++kk) {
    int n = __shfl(nv, kk);
    const float* fr = ft + ((size_t)b * NP + n) * 64;
    xbuf[wv][kk][3 + lane] = fr[lane];
    if (lane < 3) {
      const float* pp = p + ((size_t)b * NP + n) * 3;
      float qc = (lane == 0) ? qx : ((lane == 1) ? qy : qz);
      xbuf[wv][kk][lane] = __fsub_rn(pp[lane], qc);
    }
    if (lane == 3) xbuf[wv][kk][67] = 0.0f;
  }
  __syncthreads();
  // conv1: lane = channel o; preload its w row into regs
  const float4* wr = (const float4*)(w1p + lane * 68);
  float4 wreg[17];
  #pragma unroll
  for (int c4 = 0; c4 < 17; ++c4) wreg[c4] = wr[c4];
  float ss = 0.f, qq = 0.f;
  for (int kk = 0; kk < KS; ++kk) {
    const float4* xr = (const float4*)(&xbuf[wv][kk][0]);
    float acc = 0.f;
    #pragma unroll
    for (int c4 = 0; c4 < 17; ++c4) {
      float4 w = wreg[c4]; float4 x = xr[c4];
      acc += w.x*x.x + w.y*x.y + w.z*x.z + w.w*x.w;
    }
    ss += acc; qq += acc * acc;
  }
  wbs[wv][lane] = ss; wbq[wv][lane] = qq;
  __syncthreads();
  if (threadIdx.x < 64) {
    float s  = wbs[0][threadIdx.x] + wbs[1][threadIdx.x] + wbs[2][threadIdx.x] + wbs[3][threadIdx.x];
    float s2 = wbq[0][threadIdx.x] + wbq[1][threadIdx.x] + wbq[2][threadIdx.x] + wbq[3][threadIdx.x];
    int slice = blockIdx.x & 63;
    atomicAdd(&stats1[(slice*2+0)*64 + threadIdx.x], s);
    atomicAdd(&stats1[(slice*2+1)*64 + threadIdx.x], s2);
  }
}

// ------------------------------------------------------------------
// finalize bn1 stats -> scale/shift
// ------------------------------------------------------------------
__global__ void fin1_kernel(const float* __restrict__ stats1,
                            const float* __restrict__ g, const float* __restrict__ bb,
                            float* __restrict__ sc) {
  int o = threadIdx.x;  // 64
  float s = 0.f, q = 0.f;
  for (int sl = 0; sl < 64; ++sl) { s += stats1[(sl*2+0)*64+o]; q += stats1[(sl*2+1)*64+o]; }
  const float cnt = (float)(BB * MQ * KS);
  float mean = s / cnt;
  float var = q / cnt - mean * mean;
  float rstd = 1.0f / sqrtf(var + 1e-5f);
  float gs = g[o] * rstd;
  sc[o] = gs;
  sc[64+o] = bb[o] - mean * gs;
}

__global__ void fin2_kernel(const float* __restrict__ stats2,
                            const float* __restrict__ g, const float* __restrict__ bb,
                            float* __restrict__ sc) {
  int o = threadIdx.x;  // 128
  float s = 0.f, q = 0.f;
  for (int sl = 0; sl < 64; ++sl) { s += stats2[(sl*2+0)*128+o]; q += stats2[(sl*2+1)*128+o]; }
  const float cnt = (float)(BB * MQ * KS);
  float mean = s / cnt;
  float var = q / cnt - mean * mean;
  float rstd = 1.0f / sqrtf(var + 1e-5f);
  float gs = g[o] * rstd;
  sc[o] = gs;
  sc[128+o] = bb[o] - mean * gs;
}

// ------------------------------------------------------------------
// P2: recompute conv1, bn1+relu (h overwrites x rows in LDS), conv2,
// per-channel stats2 + per-query max over K (bn2 commutes with max).
// ------------------------------------------------------------------
__global__ __launch_bounds__(256) void p2_kernel(
    const float* __restrict__ p, const float* __restrict__ newp,
    const float* __restrict__ ft, const int* __restrict__ nidx,
    const float* __restrict__ w1p, const float* __restrict__ w2,
    const float* __restrict__ sc1,
    float* __restrict__ stats2, float* __restrict__ maxy2) {
  __shared__ __align__(16) float xbuf[4][KS][68];
  __shared__ float wbs[4][128], wbq[4][128];
  int wv = threadIdx.x >> 6, lane = threadIdx.x & 63;
  int qid = blockIdx.x * 4 + wv;
  int b = qid >> 11;
  // gather
  int nv = (lane < KS) ? nidx[(size_t)qid * KS + lane] : 0;
  float qx = newp[qid*3], qy = newp[qid*3+1], qz = newp[qid*3+2];
  for (int kk = 0; kk < KS; ++kk) {
    int n = __shfl(nv, kk);
    const float* fr = ft + ((size_t)b * NP + n) * 64;
    xbuf[wv][kk][3 + lane] = fr[lane];
    if (lane < 3) {
      const float* pp = p + ((size_t)b * NP + n) * 3;
      float qc = (lane == 0) ? qx : ((lane == 1) ? qy : qz);
      xbuf[wv][kk][lane] = __fsub_rn(pp[lane], qc);
    }
    if (lane == 3) xbuf[wv][kk][67] = 0.0f;
  }
  __syncthreads();
  // conv1 + bn1 + relu; h[o=lane][kk] written into xbuf[wv][kk][lane]
  {
    const float4* wr = (const float4*)(w1p + lane * 68);
    float4 wreg[17];
    #pragma unroll
    for (int c4 = 0; c4 < 17; ++c4) wreg[c4] = wr[c4];
    float s1v = sc1[lane], t1v = sc1[64 + lane];
    for (int kk = 0; kk < KS; ++kk) {
      const float4* xr = (const float4*)(&xbuf[wv][kk][0]);
      float acc = 0.f;
      #pragma unroll
      for (int c4 = 0; c4 < 17; ++c4) {
        float4 w = wreg[c4]; float4 x = xr[c4];
        acc += w.x*x.x + w.y*x.y + w.z*x.z + w.w*x.w;
      }
      float h = fmaxf(0.0f, fmaf(acc, s1v, t1v));
      xbuf[wv][kk][lane] = h;   // safe: whole row kk consumed by all lanes (lockstep)
    }
  }
  // conv2: lane computes channels lane and lane+64
  const float4* w2a = (const float4*)(w2 + (size_t)lane * 64);
  const float4* w2b = (const float4*)(w2 + (size_t)(lane + 64) * 64);
  float4 wra[16], wrb[16];
  #pragma unroll
  for (int c4 = 0; c4 < 16; ++c4) { wra[c4] = w2a[c4]; wrb[c4] = w2b[c4]; }
  float ss0 = 0.f, qq0 = 0.f, mx0 = -INFINITY;
  float ss1 = 0.f, qq1 = 0.f, mx1 = -INFINITY;
  for (int kk = 0; kk < KS; ++kk) {
    const float4* hr = (const float4*)(&xbuf[wv][kk][0]);
    float a0 = 0.f, a1 = 0.f;
    #pragma unroll
    for (int c4 = 0; c4 < 16; ++c4) {
      float4 h4 = hr[c4];
      float4 wa = wra[c4]; float4 wb = wrb[c4];
      a0 += wa.x*h4.x + wa.y*h4.y + wa.z*h4.z + wa.w*h4.w;
      a1 += wb.x*h4.x + wb.y*h4.y + wb.z*h4.z + wb.w*h4.w;
    }
    ss0 += a0; qq0 += a0*a0; mx0 = fmaxf(mx0, a0);
    ss1 += a1; qq1 += a1*a1; mx1 = fmaxf(mx1, a1);
  }
  maxy2[(size_t)qid * 128 + lane] = mx0;
  maxy2[(size_t)qid * 128 + 64 + lane] = mx1;
  wbs[wv][lane] = ss0; wbs[wv][64+lane] = ss1;
  wbq[wv][lane] = qq0; wbq[wv][64+lane] = qq1;
  __syncthreads();
  if (threadIdx.x < 128) {
    float s  = wbs[0][threadIdx.x] + wbs[1][threadIdx.x] + wbs[2][threadIdx.x] + wbs[3][threadIdx.x];
    float s2 = wbq[0][threadIdx.x] + wbq[1][threadIdx.x] + wbq[2][threadIdx.x] + wbq[3][threadIdx.x];
    int slice = blockIdx.x & 63;
    atomicAdd(&stats2[(slice*2+0)*128 + threadIdx.x], s);
    atomicAdd(&stats2[(slice*2+1)*128 + threadIdx.x], s2);
  }
}

// ------------------------------------------------------------------
// P3: skip conv (w_skip · f[:,idx] + b_skip) + bn2 affine on max + relu
// ------------------------------------------------------------------
__global__ __launch_bounds__(256) void p3_kernel(
    const float* __restrict__ ft, const int* __restrict__ idx_i,
    const float* __restrict__ w_skip, const float* __restrict__ b_skip,
    const float* __restrict__ sc2, const float* __restrict__ maxy2,
    float* __restrict__ outf) {
  int wv = threadIdx.x >> 6, lane = threadIdx.x & 63;
  int qid = blockIdx.x * 4 + wv;
  int b = qid >> 11, m = qid & (MQ - 1);
  int n = idx_i[qid];
  const float4* f4 = (const float4*)(ft + ((size_t)b * NP + n) * 64);
  const float4* wa = (const float4*)(w_skip + (size_t)lane * 64);
  const float4* wb = (const float4*)(w_skip + (size_t)(lane + 64) * 64);
  float a0 = b_skip[lane], a1 = b_skip[lane + 64];
  #pragma unroll
  for (int c4 = 0; c4 < 16; ++c4) {
    float4 x = f4[c4]; float4 u = wa[c4]; float4 v = wb[c4];
    a0 += u.x*x.x + u.y*x.y + u.z*x.z + u.w*x.w;
    a1 += v.x*x.x + v.y*x.y + v.z*x.z + v.w*x.w;
  }
  float v0 = maxy2[(size_t)qid * 128 + lane];
  float v1 = maxy2[(size_t)qid * 128 + 64 + lane];
  float r0 = fmaxf(0.0f, fmaf(v0, sc2[lane],      sc2[128 + lane])      + a0);
  float r1 = fmaxf(0.0f, fmaf(v1, sc2[lane + 64], sc2[128 + lane + 64]) + a1);
  outf[((size_t)b * 128 + lane) * MQ + m] = r0;
  outf[((size_t)b * 128 + lane + 64) * MQ + m] = r1;
}

// ------------------------------------------------------------------
extern "C" void kernel_launch(void* const* d_in, const int* in_sizes, int n_in,
                              void* d_out, int out_size, void* d_ws, size_t ws_size,
                              hipStream_t stream) {
  (void)in_sizes; (void)n_in; (void)out_size; (void)ws_size;
  const float* p   = (const float*)d_in[0];
  const float* f   = (const float*)d_in[1];
  const float* w1  = (const float*)d_in[2];
  const float* g1  = (const float*)d_in[3];
  const float* b1  = (const float*)d_in[4];
  const float* w2  = (const float*)d_in[5];
  const float* g2  = (const float*)d_in[6];
  const float* b2  = (const float*)d_in[7];
  const float* wsk = (const float*)d_in[8];
  const float* bsk = (const float*)d_in[9];
  float* out = (float*)d_out;
  float* wsf = (float*)d_ws;

  float* ft    = wsf + WS_FT;
  int*   nidx  = (int*)(wsf + WS_NIDX);
  int*   idxi  = (int*)(wsf + WS_IDXI);
  float* st1   = wsf + WS_ST1;
  float* st2   = wsf + WS_ST2;
  float* sc1   = wsf + WS_SC1;
  float* sc2   = wsf + WS_SC2;
  float* maxy2 = wsf + WS_MAXY2;
  float* w1p   = wsf + WS_W1P;

  float* out_newp = out;
  float* out_f    = out + BB*MQ*3;

  // zero the atomic stats accumulators (st1+st2 are contiguous)
  hipMemsetAsync(st1, 0, (8192 + 16384) * sizeof(float), stream);

  transpose_f_kernel<<<dim3(NP/64, BB), 256, 0, stream>>>(f, ft);
  prep_w1_kernel<<<17, 256, 0, stream>>>(w1, w1p);
  fps_kernel<<<BB, FPS_T, 0, stream>>>(p, out, idxi);
  ballq_kernel<<<BB*MQ/4, 256, 0, stream>>>(p, out_newp, nidx);
  p1_kernel<<<BB*MQ/4, 256, 0, stream>>>(p, out_newp, ft, nidx, w1p, st1);
  fin1_kernel<<<1, 64, 0, stream>>>(st1, g1, b1, sc1);
  p2_kernel<<<BB*MQ/4, 256, 0, stream>>>(p, out_newp, ft, nidx, w1p, w2, sc1, st2, maxy2);
  fin2_kernel<<<1, 128, 0, stream>>>(st2, g2, b2, sc2);
  p3_kernel<<<BB*MQ/4, 256, 0, stream>>>(ft, idxi, wsk, bsk, sc2, maxy2, out_f);
}

// Round 5
// 2402.295 us; speedup vs baseline: 1.1758x; 1.1758x over previous
//
#include <hip/hip_runtime.h>
#include <math.h>

#define BB 4
#define NP 8192
#define CF 64
#define MQ 2048
#define KS 32

// ---- workspace layout (float indices) ----
#define WS_FT     0u         // ft: [B][N][64] transposed features (2097152 floats)
#define WS_NIDX   2097152u   // nidx: [B][M][K] int (262144)
#define WS_IDXI   2359296u   // idx int copy: [B][M] (8192)
#define WS_ST1    2367488u   // stats1 slices: [64][2][64] (8192)
#define WS_ST2    2375680u   // stats2 slices: [64][2][128] (16384)
#define WS_SC1    2392064u   // scale/shift bn1: [2][64] (128)
#define WS_SC2    2392192u   // scale/shift bn2: [2][128] (256)
#define WS_MAXY2  2392448u   // maxy2: [B*M][128] (1048576)
#define WS_W1P    3441024u   // padded w1: [64][68] (4352)

// ------------------------------------------------------------------
// transpose f [B][64][N] -> ft [B][N][64]
// ------------------------------------------------------------------
__global__ __launch_bounds__(256) void transpose_f_kernel(
    const float* __restrict__ f, float* __restrict__ ft) {
  __shared__ float tile[64][65];
  int b = blockIdx.y;
  int n0 = blockIdx.x * 64;
  int cc = threadIdx.x >> 6;   // 0..3
  int nn = threadIdx.x & 63;
  #pragma unroll
  for (int r = 0; r < 16; ++r) {
    int c = cc * 16 + r;
    tile[c][nn] = f[((size_t)b * 64 + c) * NP + n0 + nn];
  }
  __syncthreads();
  #pragma unroll
  for (int r = 0; r < 16; ++r) {
    int nl = cc * 16 + r;
    ft[((size_t)b * NP + n0 + nl) * 64 + nn] = tile[nn][nl];
  }
}

// ------------------------------------------------------------------
// pad w1 [64][67] -> w1p [64][68] (last col 0), 16B-aligned rows
// ------------------------------------------------------------------
__global__ void prep_w1_kernel(const float* __restrict__ w1, float* __restrict__ w1p) {
  int i = blockIdx.x * 256 + threadIdx.x;
  if (i < 64 * 68) {
    int o = i / 68, c = i % 68;
    w1p[i] = (c < 67) ? w1[o * 67 + c] : 0.0f;
  }
}

// ------------------------------------------------------------------
// FPS v4b: 256 threads/WG (r2 config), 32 points/thread in registers.
// r3 lesson: per-SIMD issue work is invariant in wave count; the tail
// is a serial latency chain. v4 replaces the 6-level __shfl_xor tree
// (6 x ~120cy ds_bpermute latency) with a DPP reduction (VALU-class):
// row_shr:1/2/4/8 + row_bcast15 + row_bcast31 leaves the wave max in
// lane 63. u64 key = (f32bits(dmin)<<32)|~idx (dmin>=0 -> bit-ordered;
// ties -> largest ~idx = smallest idx; DPP bound_ctrl identity 0 never
// beats a real key since ~idx >= 0xFFFFE000). Math sequence identical
// to r2/r3 (rn sub/mul/add + fminf, no FMA) -> bit-exact selection.
// Tail: lane63 of each of 4 waves does ONE ds atomicMax into a
// triple-buffered slot (r3's proven protocol), single barrier/iter.
// v4b fix: dpp ctrl must be a compile-time constant -> template param.
// ------------------------------------------------------------------
#define FPS_T 256
#define PPT 32

template <int CTRL>
__device__ __forceinline__ unsigned long long dpp_max_step(unsigned long long k) {
  int lo = (int)(unsigned)k;
  int hi = (int)(unsigned)(k >> 32);
  int slo = __builtin_amdgcn_update_dpp(0, lo, CTRL, 0xF, 0xF, true);
  int shi = __builtin_amdgcn_update_dpp(0, hi, CTRL, 0xF, 0xF, true);
  unsigned long long s =
      ((unsigned long long)(unsigned)shi << 32) | (unsigned long long)(unsigned)slo;
  return s > k ? s : k;
}

__global__ __launch_bounds__(256, 1) void fps_kernel(
    const float* __restrict__ p, float* __restrict__ out, int* __restrict__ idx_i) {
  __shared__ float spx[NP], spy[NP], spz[NP];               // 96 KB
  __shared__ unsigned long long cnd[3];
  int b = blockIdx.x;
  const float* pb = p + (size_t)b * NP * 3;
  float* out_newp = out;                               // [B][M][3]
  float* out_idxf = out + BB*MQ*3 + (size_t)BB*128*MQ; // [B][M] as float
  int t = threadIdx.x;

  float px[PPT], py[PPT], pz[PPT], dmin[PPT];
  #pragma unroll
  for (int s = 0; s < PPT; ++s) {
    int i = s * FPS_T + t;
    float x = pb[i*3+0], y = pb[i*3+1], z = pb[i*3+2];
    px[s] = x; py[s] = y; pz[s] = z;
    spx[i] = x; spy[i] = y; spz[i] = z;
    dmin[s] = INFINITY;
  }
  if (t < 3) cnd[t] = 0ull;
  __syncthreads();
  float lx = spx[0], ly = spy[0], lz = spz[0];
  if (t == 0) {
    out_idxf[b*MQ] = 0.0f;
    idx_i[b*MQ] = 0;
    out_newp[(size_t)(b*MQ)*3 + 0] = lx;
    out_newp[(size_t)(b*MQ)*3 + 1] = ly;
    out_newp[(size_t)(b*MQ)*3 + 2] = lz;
  }

  for (int j = 1; j < MQ; ++j) {
    // two independent argmax chains (even/odd slots) halve dep depth
    float bv0 = -1.0f, bv1 = -1.0f;
    unsigned bn0 = 0u, bn1 = 0u;
    #pragma unroll
    for (int s = 0; s < PPT; s += 2) {
      {
        float dx = __fsub_rn(px[s], lx);
        float dy = __fsub_rn(py[s], ly);
        float dz = __fsub_rn(pz[s], lz);
        float d = __fadd_rn(__fadd_rn(__fmul_rn(dx,dx), __fmul_rn(dy,dy)), __fmul_rn(dz,dz));
        float dm = fminf(dmin[s], d);
        dmin[s] = dm;
        bool gt = dm > bv0;           // strict > keeps earliest slot
        bv0 = gt ? dm : bv0;
        bn0 = gt ? ~(unsigned)(s * FPS_T + t) : bn0;
      }
      {
        float dx = __fsub_rn(px[s+1], lx);
        float dy = __fsub_rn(py[s+1], ly);
        float dz = __fsub_rn(pz[s+1], lz);
        float d = __fadd_rn(__fadd_rn(__fmul_rn(dx,dx), __fmul_rn(dy,dy)), __fmul_rn(dz,dz));
        float dm = fminf(dmin[s+1], d);
        dmin[s+1] = dm;
        bool gt = dm > bv1;
        bv1 = gt ? dm : bv1;
        bn1 = gt ? ~(unsigned)((s+1) * FPS_T + t) : bn1;
      }
    }
    unsigned long long k0 =
        ((unsigned long long)__float_as_uint(bv0) << 32) | (unsigned long long)bn0;
    unsigned long long k1 =
        ((unsigned long long)__float_as_uint(bv1) << 32) | (unsigned long long)bn1;
    unsigned long long key = k0 > k1 ? k0 : k1;   // ties: larger ~idx = smaller idx
    // DPP wave-max: result lands in lane 63
    key = dpp_max_step<0x111>(key);  // row_shr:1
    key = dpp_max_step<0x112>(key);  // row_shr:2
    key = dpp_max_step<0x114>(key);  // row_shr:4
    key = dpp_max_step<0x118>(key);  // row_shr:8
    key = dpp_max_step<0x142>(key);  // row_bcast15
    key = dpp_max_step<0x143>(key);  // row_bcast31
    int slot = j % 3;
    if ((t & 63) == 63) atomicMax(&cnd[slot], key);
    __syncthreads();
    unsigned long long kw = cnd[slot];
    if (t == 0) cnd[(j + 2) % 3] = 0ull;
    int wi = (int)(~(unsigned)kw);
    lx = spx[wi]; ly = spy[wi]; lz = spz[wi];   // LDS broadcast (same addr)
    if (t == 0) {
      out_idxf[b*MQ + j] = (float)wi;
      idx_i[b*MQ + j] = wi;
      float* np_ = &out_newp[(size_t)(b*MQ + j) * 3];
      np_[0] = lx; np_[1] = ly; np_[2] = lz;
    }
  }
}

// ------------------------------------------------------------------
// ball query: one wave per query. Mirrors |q|^2+|p|^2-2*dot with rn
// ops; threshold is float( double(0.1)*double(0.1) ).
// ------------------------------------------------------------------
__global__ __launch_bounds__(256) void ballq_kernel(
    const float* __restrict__ p, const float* __restrict__ newp,
    int* __restrict__ nidx) {
  int qid = blockIdx.x * 4 + (threadIdx.x >> 6);   // b*M+m
  int lane = threadIdx.x & 63;
  int b = qid >> 11;
  const float* pb = p + (size_t)b * NP * 3;
  float qx = newp[qid*3], qy = newp[qid*3+1], qz = newp[qid*3+2];
  float sq_q = __fadd_rn(__fadd_rn(__fmul_rn(qx,qx), __fmul_rn(qy,qy)), __fmul_rn(qz,qz));
  const float R2 = (float)(0.1 * 0.1);   // 0.009999999776482582f
  int found = 0, first = -1;
  int* outp = nidx + (size_t)qid * KS;
  for (int base = 0; base < NP; base += 64) {
    int n = base + lane;
    float x = pb[n*3], y = pb[n*3+1], z = pb[n*3+2];
    float sq_p = __fadd_rn(__fadd_rn(__fmul_rn(x,x), __fmul_rn(y,y)), __fmul_rn(z,z));
    float dot  = __fadd_rn(__fadd_rn(__fmul_rn(qx,x), __fmul_rn(qy,y)), __fmul_rn(qz,z));
    float d2   = __fadd_rn(__fadd_rn(sq_q, sq_p), __fmul_rn(-2.0f, dot));
    bool hit = d2 < R2;
    unsigned long long mask = __ballot(hit);
    if (mask) {
      if (first < 0) first = base + __builtin_ctzll(mask);
      int cnt = __popcll(mask);
      if (found < KS) {
        int rank = __popcll(mask & ((1ull << lane) - 1ull));
        if (hit && found + rank < KS) outp[found + rank] = n;
      }
      found += cnt;
      if (found >= KS) break;
    }
  }
  int fcl = found < KS ? found : KS;
  int padv = first < 0 ? 0 : first;
  if (lane >= fcl && lane < KS) outp[lane] = padv;
}

// ------------------------------------------------------------------
// P1: conv1 over gathered x, accumulate per-channel sum/sumsq.
// One wave per query, lane = output channel.
// ------------------------------------------------------------------
__global__ __launch_bounds__(256) void p1_kernel(
    const float* __restrict__ p, const float* __restrict__ newp,
    const float* __restrict__ ft, const int* __restrict__ nidx,
    const float* __restrict__ w1p, float* __restrict__ stats1) {
  __shared__ __align__(16) float xbuf[4][KS][68];
  __shared__ float wbs[4][64], wbq[4][64];
  int wv = threadIdx.x >> 6, lane = threadIdx.x & 63;
  int qid = blockIdx.x * 4 + wv;
  int b = qid >> 11;
  // gather x = [dp(3) | fj(64) | 0]
  int nv = (lane < KS) ? nidx[(size_t)qid * KS + lane] : 0;
  float qx = newp[qid*3], qy = newp[qid*3+1], qz = newp[qid*3+2];
  for (int kk = 0; kk < KS; ++kk) {
    int n = __shfl(nv, kk);
    const float* fr = ft + ((size_t)b * NP + n) * 64;
    xbuf[wv][kk][3 + lane] = fr[lane];
    if (lane < 3) {
      const float* pp = p + ((size_t)b * NP + n) * 3;
      float qc = (lane == 0) ? qx : ((lane == 1) ? qy : qz);
      xbuf[wv][kk][lane] = __fsub_rn(pp[lane], qc);
    }
    if (lane == 3) xbuf[wv][kk][67] = 0.0f;
  }
  __syncthreads();
  // conv1: lane = channel o; preload its w row into regs
  const float4* wr = (const float4*)(w1p + lane * 68);
  float4 wreg[17];
  #pragma unroll
  for (int c4 = 0; c4 < 17; ++c4) wreg[c4] = wr[c4];
  float ss = 0.f, qq = 0.f;
  for (int kk = 0; kk < KS; ++kk) {
    const float4* xr = (const float4*)(&xbuf[wv][kk][0]);
    float acc = 0.f;
    #pragma unroll
    for (int c4 = 0; c4 < 17; ++c4) {
      float4 w = wreg[c4]; float4 x = xr[c4];
      acc += w.x*x.x + w.y*x.y + w.z*x.z + w.w*x.w;
    }
    ss += acc; qq += acc * acc;
  }
  wbs[wv][lane] = ss; wbq[wv][lane] = qq;
  __syncthreads();
  if (threadIdx.x < 64) {
    float s  = wbs[0][threadIdx.x] + wbs[1][threadIdx.x] + wbs[2][threadIdx.x] + wbs[3][threadIdx.x];
    float s2 = wbq[0][threadIdx.x] + wbq[1][threadIdx.x] + wbq[2][threadIdx.x] + wbq[3][threadIdx.x];
    int slice = blockIdx.x & 63;
    atomicAdd(&stats1[(slice*2+0)*64 + threadIdx.x], s);
    atomicAdd(&stats1[(slice*2+1)*64 + threadIdx.x], s2);
  }
}

// ------------------------------------------------------------------
// finalize bn1 stats -> scale/shift
// ------------------------------------------------------------------
__global__ void fin1_kernel(const float* __restrict__ stats1,
                            const float* __restrict__ g, const float* __restrict__ bb,
                            float* __restrict__ sc) {
  int o = threadIdx.x;  // 64
  float s = 0.f, q = 0.f;
  for (int sl = 0; sl < 64; ++sl) { s += stats1[(sl*2+0)*64+o]; q += stats1[(sl*2+1)*64+o]; }
  const float cnt = (float)(BB * MQ * KS);
  float mean = s / cnt;
  float var = q / cnt - mean * mean;
  float rstd = 1.0f / sqrtf(var + 1e-5f);
  float gs = g[o] * rstd;
  sc[o] = gs;
  sc[64+o] = bb[o] - mean * gs;
}

__global__ void fin2_kernel(const float* __restrict__ stats2,
                            const float* __restrict__ g, const float* __restrict__ bb,
                            float* __restrict__ sc) {
  int o = threadIdx.x;  // 128
  float s = 0.f, q = 0.f;
  for (int sl = 0; sl < 64; ++sl) { s += stats2[(sl*2+0)*128+o]; q += stats2[(sl*2+1)*128+o]; }
  const float cnt = (float)(BB * MQ * KS);
  float mean = s / cnt;
  float var = q / cnt - mean * mean;
  float rstd = 1.0f / sqrtf(var + 1e-5f);
  float gs = g[o] * rstd;
  sc[o] = gs;
  sc[128+o] = bb[o] - mean * gs;
}

// ------------------------------------------------------------------
// P2: recompute conv1, bn1+relu (h overwrites x rows in LDS), conv2,
// per-channel stats2 + per-query max over K (bn2 commutes with max).
// ------------------------------------------------------------------
__global__ __launch_bounds__(256) void p2_kernel(
    const float* __restrict__ p, const float* __restrict__ newp,
    const float* __restrict__ ft, const int* __restrict__ nidx,
    const float* __restrict__ w1p, const float* __restrict__ w2,
    const float* __restrict__ sc1,
    float* __restrict__ stats2, float* __restrict__ maxy2) {
  __shared__ __align__(16) float xbuf[4][KS][68];
  __shared__ float wbs[4][128], wbq[4][128];
  int wv = threadIdx.x >> 6, lane = threadIdx.x & 63;
  int qid = blockIdx.x * 4 + wv;
  int b = qid >> 11;
  // gather
  int nv = (lane < KS) ? nidx[(size_t)qid * KS + lane] : 0;
  float qx = newp[qid*3], qy = newp[qid*3+1], qz = newp[qid*3+2];
  for (int kk = 0; kk < KS; ++kk) {
    int n = __shfl(nv, kk);
    const float* fr = ft + ((size_t)b * NP + n) * 64;
    xbuf[wv][kk][3 + lane] = fr[lane];
    if (lane < 3) {
      const float* pp = p + ((size_t)b * NP + n) * 3;
      float qc = (lane == 0) ? qx : ((lane == 1) ? qy : qz);
      xbuf[wv][kk][lane] = __fsub_rn(pp[lane], qc);
    }
    if (lane == 3) xbuf[wv][kk][67] = 0.0f;
  }
  __syncthreads();
  // conv1 + bn1 + relu; h[o=lane][kk] written into xbuf[wv][kk][lane]
  {
    const float4* wr = (const float4*)(w1p + lane * 68);
    float4 wreg[17];
    #pragma unroll
    for (int c4 = 0; c4 < 17; ++c4) wreg[c4] = wr[c4];
    float s1v = sc1[lane], t1v = sc1[64 + lane];
    for (int kk = 0; kk < KS; ++kk) {
      const float4* xr = (const float4*)(&xbuf[wv][kk][0]);
      float acc = 0.f;
      #pragma unroll
      for (int c4 = 0; c4 < 17; ++c4) {
        float4 w = wreg[c4]; float4 x = xr[c4];
        acc += w.x*x.x + w.y*x.y + w.z*x.z + w.w*x.w;
      }
      float h = fmaxf(0.0f, fmaf(acc, s1v, t1v));
      xbuf[wv][kk][lane] = h;   // safe: whole row kk consumed by all lanes (lockstep)
    }
  }
  // conv2: lane computes channels lane and lane+64
  const float4* w2a = (const float4*)(w2 + (size_t)lane * 64);
  const float4* w2b = (const float4*)(w2 + (size_t)(lane + 64) * 64);
  float4 wra[16], wrb[16];
  #pragma unroll
  for (int c4 = 0; c4 < 16; ++c4) { wra[c4] = w2a[c4]; wrb[c4] = w2b[c4]; }
  float ss0 = 0.f, qq0 = 0.f, mx0 = -INFINITY;
  float ss1 = 0.f, qq1 = 0.f, mx1 = -INFINITY;
  for (int kk = 0; kk < KS; ++kk) {
    const float4* hr = (const float4*)(&xbuf[wv][kk][0]);
    float a0 = 0.f, a1 = 0.f;
    #pragma unroll
    for (int c4 = 0; c4 < 16; ++c4) {
      float4 h4 = hr[c4];
      float4 wa = wra[c4]; float4 wb = wrb[c4];
      a0 += wa.x*h4.x + wa.y*h4.y + wa.z*h4.z + wa.w*h4.w;
      a1 += wb.x*h4.x + wb.y*h4.y + wb.z*h4.z + wb.w*h4.w;
    }
    ss0 += a0; qq0 += a0*a0; mx0 = fmaxf(mx0, a0);
    ss1 += a1; qq1 += a1*a1; mx1 = fmaxf(mx1, a1);
  }
  maxy2[(size_t)qid * 128 + lane] = mx0;
  maxy2[(size_t)qid * 128 + 64 + lane] = mx1;
  wbs[wv][lane] = ss0; wbs[wv][64+lane] = ss1;
  wbq[wv][lane] = qq0; wbq[wv][64+lane] = qq1;
  __syncthreads();
  if (threadIdx.x < 128) {
    float s  = wbs[0][threadIdx.x] + wbs[1][threadIdx.x] + wbs[2][threadIdx.x] + wbs[3][threadIdx.x];
    float s2 = wbq[0][threadIdx.x] + wbq[1][threadIdx.x] + wbq[2][threadIdx.x] + wbq[3][threadIdx.x];
    int slice = blockIdx.x & 63;
    atomicAdd(&stats2[(slice*2+0)*128 + threadIdx.x], s);
    atomicAdd(&stats2[(slice*2+1)*128 + threadIdx.x], s2);
  }
}

// ------------------------------------------------------------------
// P3: skip conv (w_skip · f[:,idx] + b_skip) + bn2 affine on max + relu
// ------------------------------------------------------------------
__global__ __launch_bounds__(256) void p3_kernel(
    const float* __restrict__ ft, const int* __restrict__ idx_i,
    const float* __restrict__ w_skip, const float* __restrict__ b_skip,
    const float* __restrict__ sc2, const float* __restrict__ maxy2,
    float* __restrict__ outf) {
  int wv = threadIdx.x >> 6, lane = threadIdx.x & 63;
  int qid = blockIdx.x * 4 + wv;
  int b = qid >> 11, m = qid & (MQ - 1);
  int n = idx_i[qid];
  const float4* f4 = (const float4*)(ft + ((size_t)b * NP + n) * 64);
  const float4* wa = (const float4*)(w_skip + (size_t)lane * 64);
  const float4* wb = (const float4*)(w_skip + (size_t)(lane + 64) * 64);
  float a0 = b_skip[lane], a1 = b_skip[lane + 64];
  #pragma unroll
  for (int c4 = 0; c4 < 16; ++c4) {
    float4 x = f4[c4]; float4 u = wa[c4]; float4 v = wb[c4];
    a0 += u.x*x.x + u.y*x.y + u.z*x.z + u.w*x.w;
    a1 += v.x*x.x + v.y*x.y + v.z*x.z + v.w*x.w;
  }
  float v0 = maxy2[(size_t)qid * 128 + lane];
  float v1 = maxy2[(size_t)qid * 128 + 64 + lane];
  float r0 = fmaxf(0.0f, fmaf(v0, sc2[lane],      sc2[128 + lane])      + a0);
  float r1 = fmaxf(0.0f, fmaf(v1, sc2[lane + 64], sc2[128 + lane + 64]) + a1);
  outf[((size_t)b * 128 + lane) * MQ + m] = r0;
  outf[((size_t)b * 128 + lane + 64) * MQ + m] = r1;
}

// ------------------------------------------------------------------
extern "C" void kernel_launch(void* const* d_in, const int* in_sizes, int n_in,
                              void* d_out, int out_size, void* d_ws, size_t ws_size,
                              hipStream_t stream) {
  (void)in_sizes; (void)n_in; (void)out_size; (void)ws_size;
  const float* p   = (const float*)d_in[0];
  const float* f   = (const float*)d_in[1];
  const float* w1  = (const float*)d_in[2];
  const float* g1  = (const float*)d_in[3];
  const float* b1  = (const float*)d_in[4];
  const float* w2  = (const float*)d_in[5];
  const float* g2  = (const float*)d_in[6];
  const float* b2  = (const float*)d_in[7];
  const float* wsk = (const float*)d_in[8];
  const float* bsk = (const float*)d_in[9];
  float* out = (float*)d_out;
  float* wsf = (float*)d_ws;

  float* ft    = wsf + WS_FT;
  int*   nidx  = (int*)(wsf + WS_NIDX);
  int*   idxi  = (int*)(wsf + WS_IDXI);
  float* st1   = wsf + WS_ST1;
  float* st2   = wsf + WS_ST2;
  float* sc1   = wsf + WS_SC1;
  float* sc2   = wsf + WS_SC2;
  float* maxy2 = wsf + WS_MAXY2;
  float* w1p   = wsf + WS_W1P;

  float* out_newp = out;
  float* out_f    = out + BB*MQ*3;

  // zero the atomic stats accumulators (st1+st2 are contiguous)
  (void)hipMemsetAsync(st1, 0, (8192 + 16384) * sizeof(float), stream);

  transpose_f_kernel<<<dim3(NP/64, BB), 256, 0, stream>>>(f, ft);
  prep_w1_kernel<<<17, 256, 0, stream>>>(w1, w1p);
  fps_kernel<<<BB, FPS_T, 0, stream>>>(p, out, idxi);
  ballq_kernel<<<BB*MQ/4, 256, 0, stream>>>(p, out_newp, nidx);
  p1_kernel<<<BB*MQ/4, 256, 0, stream>>>(p, out_newp, ft, nidx, w1p, st1);
  fin1_kernel<<<1, 64, 0, stream>>>(st1, g1, b1, sc1);
  p2_kernel<<<BB*MQ/4, 256, 0, stream>>>(p, out_newp, ft, nidx, w1p, w2, sc1, st2, maxy2);
  fin2_kernel<<<1, 128, 0, stream>>>(st2, g2, b2, sc2);
  p3_kernel<<<BB*MQ/4, 256, 0, stream>>>(ft, idxi, wsk, bsk, sc2, maxy2, out_f);
}

// Round 6
// 2158.464 us; speedup vs baseline: 1.3086x; 1.1130x over previous
//
#include <hip/hip_runtime.h>
#include <math.h>

#define BB 4
#define NP 8192
#define CF 64
#define MQ 2048
#define KS 32

// ---- workspace layout (float indices) ----
#define WS_FT     0u         // ft: [B][N][64] transposed features (2097152 floats)
#define WS_NIDX   2097152u   // nidx: [B][M][K] int (262144)
#define WS_IDXI   2359296u   // idx int copy: [B][M] (8192)
#define WS_ST1    2367488u   // stats1 slices: [64][2][64] (8192)
#define WS_ST2    2375680u   // stats2 slices: [64][2][128] (16384)
#define WS_SC1    2392064u   // scale/shift bn1: [2][64] (128)
#define WS_SC2    2392192u   // scale/shift bn2: [2][128] (256)
#define WS_MAXY2  2392448u   // maxy2: [B*M][128] (1048576)
#define WS_W1P    3441024u   // padded w1: [64][68] (4352)

typedef float v2f __attribute__((ext_vector_type(2)));

// ------------------------------------------------------------------
// transpose f [B][64][N] -> ft [B][N][64]
// ------------------------------------------------------------------
__global__ __launch_bounds__(256) void transpose_f_kernel(
    const float* __restrict__ f, float* __restrict__ ft) {
  __shared__ float tile[64][65];
  int b = blockIdx.y;
  int n0 = blockIdx.x * 64;
  int cc = threadIdx.x >> 6;   // 0..3
  int nn = threadIdx.x & 63;
  #pragma unroll
  for (int r = 0; r < 16; ++r) {
    int c = cc * 16 + r;
    tile[c][nn] = f[((size_t)b * 64 + c) * NP + n0 + nn];
  }
  __syncthreads();
  #pragma unroll
  for (int r = 0; r < 16; ++r) {
    int nl = cc * 16 + r;
    ft[((size_t)b * NP + n0 + nl) * 64 + nn] = tile[nn][nl];
  }
}

// ------------------------------------------------------------------
// pad w1 [64][67] -> w1p [64][68] (last col 0), 16B-aligned rows
// ------------------------------------------------------------------
__global__ void prep_w1_kernel(const float* __restrict__ w1, float* __restrict__ w1p) {
  int i = blockIdx.x * 256 + threadIdx.x;
  if (i < 64 * 68) {
    int o = i / 68, c = i % 68;
    w1p[i] = (c < 67) ? w1[o * 67 + c] : 0.0f;
  }
}

// ------------------------------------------------------------------
// FPS v5: 256 threads/WG, 32 points/thread (16 float2 pairs).
// r5 lesson: t==0's per-iter global stores force a vmcnt(0) drain at
// every __syncthreads (all waves wait on wave0's HBM store ack).
// v5: (1) NO global ops in the loop — winner goes to LDS win[],
// idx/new_p written in a bulk coalesced epilogue; barrier drains lgkm
// only. (2) packed-f32 scan: v_pk_add/mul_f32 via float2 with
// fp contract(off) -> plain IEEE rn mul/add, bit-identical to the
// scalar __fmul_rn/__fadd_rn sequence ((dx*dx+dy*dy)+dz*dz, fminf).
// (3) coords in one float4 LDS array (ds_read_b128 broadcast).
// Argmax: dual strict-> chains (even=.x / odd=.y slots), merged via
// u64 key (f32bits(dmin)<<32)|~idx — max picks largest dmin, ties ->
// smallest idx (first occurrence). DPP wave-max (row_shr 1/2/4/8 +
// bcast15/31, result lane 63), one ds atomicMax per wave into a
// triple-buffered slot, single barrier per iteration.
// ------------------------------------------------------------------
#define FPS_T 256
#define PPT 32

template <int CTRL>
__device__ __forceinline__ unsigned long long dpp_max_step(unsigned long long k) {
  int lo = (int)(unsigned)k;
  int hi = (int)(unsigned)(k >> 32);
  int slo = __builtin_amdgcn_update_dpp(0, lo, CTRL, 0xF, 0xF, true);
  int shi = __builtin_amdgcn_update_dpp(0, hi, CTRL, 0xF, 0xF, true);
  unsigned long long s =
      ((unsigned long long)(unsigned)shi << 32) | (unsigned long long)(unsigned)slo;
  return s > k ? s : k;
}

__global__ __launch_bounds__(256, 1) void fps_kernel(
    const float* __restrict__ p, float* __restrict__ out, int* __restrict__ idx_i) {
#pragma clang fp contract(off)
  __shared__ float4 sp4[NP];                 // 128 KB: xyz + pad
  __shared__ int win[MQ];                    // 8 KB winner indices
  __shared__ unsigned long long cnd[3];
  int b = blockIdx.x;
  const float* pb = p + (size_t)b * NP * 3;
  float* out_newp = out;                               // [B][M][3]
  float* out_idxf = out + BB*MQ*3 + (size_t)BB*128*MQ; // [B][M] as float
  int t = threadIdx.x;

  v2f px2[16], py2[16], pz2[16], dmin2[16];
  #pragma unroll
  for (int k = 0; k < 16; ++k) {
    int i0 = (2*k) * FPS_T + t;
    int i1 = i0 + FPS_T;
    float x0 = pb[i0*3+0], y0 = pb[i0*3+1], z0 = pb[i0*3+2];
    float x1 = pb[i1*3+0], y1 = pb[i1*3+1], z1 = pb[i1*3+2];
    px2[k] = (v2f){x0, x1}; py2[k] = (v2f){y0, y1}; pz2[k] = (v2f){z0, z1};
    sp4[i0] = make_float4(x0, y0, z0, 0.0f);
    sp4[i1] = make_float4(x1, y1, z1, 0.0f);
    dmin2[k] = (v2f){INFINITY, INFINITY};
  }
  if (t < 3) cnd[t] = 0ull;
  if (t == 0) win[0] = 0;
  __syncthreads();
  float lx = sp4[0].x, ly = sp4[0].y, lz = sp4[0].z;
  unsigned nt = ~(unsigned)t;

  for (int j = 1; j < MQ; ++j) {
#pragma clang fp contract(off)
    v2f l2x = (v2f){lx, lx}, l2y = (v2f){ly, ly}, l2z = (v2f){lz, lz};
    // dual strict-> argmax chains: chain0 = even slots (.x), chain1 = odd (.y)
    float bv0 = -1.0f, bv1 = -1.0f;
    unsigned bn0 = 0u, bn1 = 0u;
    #pragma unroll
    for (int k = 0; k < 16; ++k) {
      v2f dx = px2[k] - l2x;
      v2f dy = py2[k] - l2y;
      v2f dz = pz2[k] - l2z;
      v2f dd = ((dx*dx) + (dy*dy)) + (dz*dz);
      v2f dm = __builtin_elementwise_min(dmin2[k], dd);
      dmin2[k] = dm;
      float m0 = dm.x, m1 = dm.y;
      bool g0 = m0 > bv0;                 // strict > keeps earliest slot
      bv0 = g0 ? m0 : bv0;
      bn0 = g0 ? (nt - (unsigned)((2*k) * FPS_T)) : bn0;      // ~((2k)*256+t)
      bool g1 = m1 > bv1;
      bv1 = g1 ? m1 : bv1;
      bn1 = g1 ? (nt - (unsigned)((2*k+1) * FPS_T)) : bn1;    // ~((2k+1)*256+t)
    }
    unsigned long long k0 =
        ((unsigned long long)__float_as_uint(bv0) << 32) | (unsigned long long)bn0;
    unsigned long long k1 =
        ((unsigned long long)__float_as_uint(bv1) << 32) | (unsigned long long)bn1;
    unsigned long long key = k0 > k1 ? k0 : k1;   // ties: larger ~idx = smaller idx
    // DPP wave-max: result lands in lane 63
    key = dpp_max_step<0x111>(key);  // row_shr:1
    key = dpp_max_step<0x112>(key);  // row_shr:2
    key = dpp_max_step<0x114>(key);  // row_shr:4
    key = dpp_max_step<0x118>(key);  // row_shr:8
    key = dpp_max_step<0x142>(key);  // row_bcast15
    key = dpp_max_step<0x143>(key);  // row_bcast31
    int slot = j % 3;
    if ((t & 63) == 63) atomicMax(&cnd[slot], key);
    __syncthreads();                 // lgkm drain only: no global ops in loop
    unsigned long long kw = cnd[slot];
    if (t == 0) cnd[(j + 2) % 3] = 0ull;
    int wi = (int)(~(unsigned)kw);
    float4 c = sp4[wi];              // one ds_read_b128, same-addr broadcast
    lx = c.x; ly = c.y; lz = c.z;
    if (t == 0) win[j] = wi;
  }

  __syncthreads();
  // bulk coalesced epilogue: idx (float + int) and new_p from LDS
  #pragma unroll
  for (int k = 0; k < MQ / FPS_T; ++k) {
    int j = k * FPS_T + t;
    int wi = win[j];
    out_idxf[b*MQ + j] = (float)wi;
    idx_i[b*MQ + j] = wi;
    float4 c = sp4[wi];
    float* np_ = &out_newp[(size_t)(b*MQ + j) * 3];
    np_[0] = c.x; np_[1] = c.y; np_[2] = c.z;
  }
}

// ------------------------------------------------------------------
// ball query: one wave per query. Mirrors |q|^2+|p|^2-2*dot with rn
// ops; threshold is float( double(0.1)*double(0.1) ).
// ------------------------------------------------------------------
__global__ __launch_bounds__(256) void ballq_kernel(
    const float* __restrict__ p, const float* __restrict__ newp,
    int* __restrict__ nidx) {
  int qid = blockIdx.x * 4 + (threadIdx.x >> 6);   // b*M+m
  int lane = threadIdx.x & 63;
  int b = qid >> 11;
  const float* pb = p + (size_t)b * NP * 3;
  float qx = newp[qid*3], qy = newp[qid*3+1], qz = newp[qid*3+2];
  float sq_q = __fadd_rn(__fadd_rn(__fmul_rn(qx,qx), __fmul_rn(qy,qy)), __fmul_rn(qz,qz));
  const float R2 = (float)(0.1 * 0.1);   // 0.009999999776482582f
  int found = 0, first = -1;
  int* outp = nidx + (size_t)qid * KS;
  for (int base = 0; base < NP; base += 64) {
    int n = base + lane;
    float x = pb[n*3], y = pb[n*3+1], z = pb[n*3+2];
    float sq_p = __fadd_rn(__fadd_rn(__fmul_rn(x,x), __fmul_rn(y,y)), __fmul_rn(z,z));
    float dot  = __fadd_rn(__fadd_rn(__fmul_rn(qx,x), __fmul_rn(qy,y)), __fmul_rn(qz,z));
    float d2   = __fadd_rn(__fadd_rn(sq_q, sq_p), __fmul_rn(-2.0f, dot));
    bool hit = d2 < R2;
    unsigned long long mask = __ballot(hit);
    if (mask) {
      if (first < 0) first = base + __builtin_ctzll(mask);
      int cnt = __popcll(mask);
      if (found < KS) {
        int rank = __popcll(mask & ((1ull << lane) - 1ull));
        if (hit && found + rank < KS) outp[found + rank] = n;
      }
      found += cnt;
      if (found >= KS) break;
    }
  }
  int fcl = found < KS ? found : KS;
  int padv = first < 0 ? 0 : first;
  if (lane >= fcl && lane < KS) outp[lane] = padv;
}

// ------------------------------------------------------------------
// P1: conv1 over gathered x, accumulate per-channel sum/sumsq.
// One wave per query, lane = output channel.
// ------------------------------------------------------------------
__global__ __launch_bounds__(256) void p1_kernel(
    const float* __restrict__ p, const float* __restrict__ newp,
    const float* __restrict__ ft, const int* __restrict__ nidx,
    const float* __restrict__ w1p, float* __restrict__ stats1) {
  __shared__ __align__(16) float xbuf[4][KS][68];
  __shared__ float wbs[4][64], wbq[4][64];
  int wv = threadIdx.x >> 6, lane = threadIdx.x & 63;
  int qid = blockIdx.x * 4 + wv;
  int b = qid >> 11;
  // gather x = [dp(3) | fj(64) | 0]
  int nv = (lane < KS) ? nidx[(size_t)qid * KS + lane] : 0;
  float qx = newp[qid*3], qy = newp[qid*3+1], qz = newp[qid*3+2];
  for (int kk = 0; kk < KS; ++kk) {
    int n = __shfl(nv, kk);
    const float* fr = ft + ((size_t)b * NP + n) * 64;
    xbuf[wv][kk][3 + lane] = fr[lane];
    if (lane < 3) {
      const float* pp = p + ((size_t)b * NP + n) * 3;
      float qc = (lane == 0) ? qx : ((lane == 1) ? qy : qz);
      xbuf[wv][kk][lane] = __fsub_rn(pp[lane], qc);
    }
    if (lane == 3) xbuf[wv][kk][67] = 0.0f;
  }
  __syncthreads();
  // conv1: lane = channel o; preload its w row into regs
  const float4* wr = (const float4*)(w1p + lane * 68);
  float4 wreg[17];
  #pragma unroll
  for (int c4 = 0; c4 < 17; ++c4) wreg[c4] = wr[c4];
  float ss = 0.f, qq = 0.f;
  for (int kk = 0; kk < KS; ++kk) {
    const float4* xr = (const float4*)(&xbuf[wv][kk][0]);
    float acc = 0.f;
    #pragma unroll
    for (int c4 = 0; c4 < 17; ++c4) {
      float4 w = wreg[c4]; float4 x = xr[c4];
      acc += w.x*x.x + w.y*x.y + w.z*x.z + w.w*x.w;
    }
    ss += acc; qq += acc * acc;
  }
  wbs[wv][lane] = ss; wbq[wv][lane] = qq;
  __syncthreads();
  if (threadIdx.x < 64) {
    float s  = wbs[0][threadIdx.x] + wbs[1][threadIdx.x] + wbs[2][threadIdx.x] + wbs[3][threadIdx.x];
    float s2 = wbq[0][threadIdx.x] + wbq[1][threadIdx.x] + wbq[2][threadIdx.x] + wbq[3][threadIdx.x];
    int slice = blockIdx.x & 63;
    atomicAdd(&stats1[(slice*2+0)*64 + threadIdx.x], s);
    atomicAdd(&stats1[(slice*2+1)*64 + threadIdx.x], s2);
  }
}

// ------------------------------------------------------------------
// finalize bn1 stats -> scale/shift
// ------------------------------------------------------------------
__global__ void fin1_kernel(const float* __restrict__ stats1,
                            const float* __restrict__ g, const float* __restrict__ bb,
                            float* __restrict__ sc) {
  int o = threadIdx.x;  // 64
  float s = 0.f, q = 0.f;
  for (int sl = 0; sl < 64; ++sl) { s += stats1[(sl*2+0)*64+o]; q += stats1[(sl*2+1)*64+o]; }
  const float cnt = (float)(BB * MQ * KS);
  float mean = s / cnt;
  float var = q / cnt - mean * mean;
  float rstd = 1.0f / sqrtf(var + 1e-5f);
  float gs = g[o] * rstd;
  sc[o] = gs;
  sc[64+o] = bb[o] - mean * gs;
}

__global__ void fin2_kernel(const float* __restrict__ stats2,
                            const float* __restrict__ g, const float* __restrict__ bb,
                            float* __restrict__ sc) {
  int o = threadIdx.x;  // 128
  float s = 0.f, q = 0.f;
  for (int sl = 0; sl < 64; ++sl) { s += stats2[(sl*2+0)*128+o]; q += stats2[(sl*2+1)*128+o]; }
  const float cnt = (float)(BB * MQ * KS);
  float mean = s / cnt;
  float var = q / cnt - mean * mean;
  float rstd = 1.0f / sqrtf(var + 1e-5f);
  float gs = g[o] * rstd;
  sc[o] = gs;
  sc[128+o] = bb[o] - mean * gs;
}

// ------------------------------------------------------------------
// P2: recompute conv1, bn1+relu (h overwrites x rows in LDS), conv2,
// per-channel stats2 + per-query max over K (bn2 commutes with max).
// ------------------------------------------------------------------
__global__ __launch_bounds__(256) void p2_kernel(
    const float* __restrict__ p, const float* __restrict__ newp,
    const float* __restrict__ ft, const int* __restrict__ nidx,
    const float* __restrict__ w1p, const float* __restrict__ w2,
    const float* __restrict__ sc1,
    float* __restrict__ stats2, float* __restrict__ maxy2) {
  __shared__ __align__(16) float xbuf[4][KS][68];
  __shared__ float wbs[4][128], wbq[4][128];
  int wv = threadIdx.x >> 6, lane = threadIdx.x & 63;
  int qid = blockIdx.x * 4 + wv;
  int b = qid >> 11;
  // gather
  int nv = (lane < KS) ? nidx[(size_t)qid * KS + lane] : 0;
  float qx = newp[qid*3], qy = newp[qid*3+1], qz = newp[qid*3+2];
  for (int kk = 0; kk < KS; ++kk) {
    int n = __shfl(nv, kk);
    const float* fr = ft + ((size_t)b * NP + n) * 64;
    xbuf[wv][kk][3 + lane] = fr[lane];
    if (lane < 3) {
      const float* pp = p + ((size_t)b * NP + n) * 3;
      float qc = (lane == 0) ? qx : ((lane == 1) ? qy : qz);
      xbuf[wv][kk][lane] = __fsub_rn(pp[lane], qc);
    }
    if (lane == 3) xbuf[wv][kk][67] = 0.0f;
  }
  __syncthreads();
  // conv1 + bn1 + relu; h[o=lane][kk] written into xbuf[wv][kk][lane]
  {
    const float4* wr = (const float4*)(w1p + lane * 68);
    float4 wreg[17];
    #pragma unroll
    for (int c4 = 0; c4 < 17; ++c4) wreg[c4] = wr[c4];
    float s1v = sc1[lane], t1v = sc1[64 + lane];
    for (int kk = 0; kk < KS; ++kk) {
      const float4* xr = (const float4*)(&xbuf[wv][kk][0]);
      float acc = 0.f;
      #pragma unroll
      for (int c4 = 0; c4 < 17; ++c4) {
        float4 w = wreg[c4]; float4 x = xr[c4];
        acc += w.x*x.x + w.y*x.y + w.z*x.z + w.w*x.w;
      }
      float h = fmaxf(0.0f, fmaf(acc, s1v, t1v));
      xbuf[wv][kk][lane] = h;   // safe: whole row kk consumed by all lanes (lockstep)
    }
  }
  // conv2: lane computes channels lane and lane+64
  const float4* w2a = (const float4*)(w2 + (size_t)lane * 64);
  const float4* w2b = (const float4*)(w2 + (size_t)(lane + 64) * 64);
  float4 wra[16], wrb[16];
  #pragma unroll
  for (int c4 = 0; c4 < 16; ++c4) { wra[c4] = w2a[c4]; wrb[c4] = w2b[c4]; }
  float ss0 = 0.f, qq0 = 0.f, mx0 = -INFINITY;
  float ss1 = 0.f, qq1 = 0.f, mx1 = -INFINITY;
  for (int kk = 0; kk < KS; ++kk) {
    const float4* hr = (const float4*)(&xbuf[wv][kk][0]);
    float a0 = 0.f, a1 = 0.f;
    #pragma unroll
    for (int c4 = 0; c4 < 16; ++c4) {
      float4 h4 = hr[c4];
      float4 wa = wra[c4]; float4 wb = wrb[c4];
      a0 += wa.x*h4.x + wa.y*h4.y + wa.z*h4.z + wa.w*h4.w;
      a1 += wb.x*h4.x + wb.y*h4.y + wb.z*h4.z + wb.w*h4.w;
    }
    ss0 += a0; qq0 += a0*a0; mx0 = fmaxf(mx0, a0);
    ss1 += a1; qq1 += a1*a1; mx1 = fmaxf(mx1, a1);
  }
  maxy2[(size_t)qid * 128 + lane] = mx0;
  maxy2[(size_t)qid * 128 + 64 + lane] = mx1;
  wbs[wv][lane] = ss0; wbs[wv][64+lane] = ss1;
  wbq[wv][lane] = qq0; wbq[wv][64+lane] = qq1;
  __syncthreads();
  if (threadIdx.x < 128) {
    float s  = wbs[0][threadIdx.x] + wbs[1][threadIdx.x] + wbs[2][threadIdx.x] + wbs[3][threadIdx.x];
    float s2 = wbq[0][threadIdx.x] + wbq[1][threadIdx.x] + wbq[2][threadIdx.x] + wbq[3][threadIdx.x];
    int slice = blockIdx.x & 63;
    atomicAdd(&stats2[(slice*2+0)*128 + threadIdx.x], s);
    atomicAdd(&stats2[(slice*2+1)*128 + threadIdx.x], s2);
  }
}

// ------------------------------------------------------------------
// P3: skip conv (w_skip · f[:,idx] + b_skip) + bn2 affine on max + relu
// ------------------------------------------------------------------
__global__ __launch_bounds__(256) void p3_kernel(
    const float* __restrict__ ft, const int* __restrict__ idx_i,
    const float* __restrict__ w_skip, const float* __restrict__ b_skip,
    const float* __restrict__ sc2, const float* __restrict__ maxy2,
    float* __restrict__ outf) {
  int wv = threadIdx.x >> 6, lane = threadIdx.x & 63;
  int qid = blockIdx.x * 4 + wv;
  int b = qid >> 11, m = qid & (MQ - 1);
  int n = idx_i[qid];
  const float4* f4 = (const float4*)(ft + ((size_t)b * NP + n) * 64);
  const float4* wa = (const float4*)(w_skip + (size_t)lane * 64);
  const float4* wb = (const float4*)(w_skip + (size_t)(lane + 64) * 64);
  float a0 = b_skip[lane], a1 = b_skip[lane + 64];
  #pragma unroll
  for (int c4 = 0; c4 < 16; ++c4) {
    float4 x = f4[c4]; float4 u = wa[c4]; float4 v = wb[c4];
    a0 += u.x*x.x + u.y*x.y + u.z*x.z + u.w*x.w;
    a1 += v.x*x.x + v.y*x.y + v.z*x.z + v.w*x.w;
  }
  float v0 = maxy2[(size_t)qid * 128 + lane];
  float v1 = maxy2[(size_t)qid * 128 + 64 + lane];
  float r0 = fmaxf(0.0f, fmaf(v0, sc2[lane],      sc2[128 + lane])      + a0);
  float r1 = fmaxf(0.0f, fmaf(v1, sc2[lane + 64], sc2[128 + lane + 64]) + a1);
  outf[((size_t)b * 128 + lane) * MQ + m] = r0;
  outf[((size_t)b * 128 + lane + 64) * MQ + m] = r1;
}

// ------------------------------------------------------------------
extern "C" void kernel_launch(void* const* d_in, const int* in_sizes, int n_in,
                              void* d_out, int out_size, void* d_ws, size_t ws_size,
                              hipStream_t stream) {
  (void)in_sizes; (void)n_in; (void)out_size; (void)ws_size;
  const float* p   = (const float*)d_in[0];
  const float* f   = (const float*)d_in[1];
  const float* w1  = (const float*)d_in[2];
  const float* g1  = (const float*)d_in[3];
  const float* b1  = (const float*)d_in[4];
  const float* w2  = (const float*)d_in[5];
  const float* g2  = (const float*)d_in[6];
  const float* b2  = (const float*)d_in[7];
  const float* wsk = (const float*)d_in[8];
  const float* bsk = (const float*)d_in[9];
  float* out = (float*)d_out;
  float* wsf = (float*)d_ws;

  float* ft    = wsf + WS_FT;
  int*   nidx  = (int*)(wsf + WS_NIDX);
  int*   idxi  = (int*)(wsf + WS_IDXI);
  float* st1   = wsf + WS_ST1;
  float* st2   = wsf + WS_ST2;
  float* sc1   = wsf + WS_SC1;
  float* sc2   = wsf + WS_SC2;
  float* maxy2 = wsf + WS_MAXY2;
  float* w1p   = wsf + WS_W1P;

  float* out_newp = out;
  float* out_f    = out + BB*MQ*3;

  // zero the atomic stats accumulators (st1+st2 are contiguous)
  (void)hipMemsetAsync(st1, 0, (8192 + 16384) * sizeof(float), stream);

  transpose_f_kernel<<<dim3(NP/64, BB), 256, 0, stream>>>(f, ft);
  prep_w1_kernel<<<17, 256, 0, stream>>>(w1, w1p);
  fps_kernel<<<BB, FPS_T, 0, stream>>>(p, out, idxi);
  ballq_kernel<<<BB*MQ/4, 256, 0, stream>>>(p, out_newp, nidx);
  p1_kernel<<<BB*MQ/4, 256, 0, stream>>>(p, out_newp, ft, nidx, w1p, st1);
  fin1_kernel<<<1, 64, 0, stream>>>(st1, g1, b1, sc1);
  p2_kernel<<<BB*MQ/4, 256, 0, stream>>>(p, out_newp, ft, nidx, w1p, w2, sc1, st2, maxy2);
  fin2_kernel<<<1, 128, 0, stream>>>(st2, g2, b2, sc2);
  p3_kernel<<<BB*MQ/4, 256, 0, stream>>>(ft, idxi, wsk, bsk, sc2, maxy2, out_f);
}